// Round 16
// baseline (79.610 us; speedup 1.0000x reference)
//
#include <hip/hip_runtime.h>
#include <math.h>

#define C_CLS   19
#define H_IN    97
#define W_IN    97
#define HW_IN   (H_IN * W_IN)
#define CHW_IN  (C_CLS * HW_IN)
#define H_OUT   769
#define W_OUT   769
#define N_BATCH 4
#define NROWS   (N_BATCH * H_OUT)    // 3076
#define NXCD    8
#define IGNORE_LBL 255
#define MIN_KEPT   100000
#define NHI     110
#define ACC_STRIDE 1024
#define NSETS   64                   // striped accumulator sets (R4-proven)
#define SET_BASE 2048
#define TICKET  (SET_BASE + NSETS * 16)   // 3072: int ticket for last-block
#define WS_ZERO_FLOATS (TICKET + 16)
#define NLL_THR 0.35667494f          // -ln(0.7)
#define ROWP    100                  // padded LDS row length (>= 98)
#define BLKT    128
#define NSTAGE  15                   // ceil(19*97 / 128)

__device__ const float c_class_w[C_CLS] = {
    0.8373f, 0.918f,  0.866f,  1.0345f, 1.0166f, 0.9969f, 0.9754f,
    1.0489f, 0.8786f, 1.0023f, 0.9539f, 0.9843f, 1.1116f, 0.9037f,
    1.0865f, 1.0955f, 1.0865f, 1.1529f, 1.0507f};

// ws layout (floats):
// [4..333]   hist pred1: cnt/sum_w/sum_wnll (stride 110)
// [1028..1357] hist pred2
// [2048 + s*16 + k] striped set s (0=nv 1=w1 2=wlp1 3=cle1 4=w2 5=wlp2 6=cle2)
// [3072] ticket (as uint)

__global__ __launch_bounds__(BLKT) void ohem_row(
    const float* __restrict__ pred1, const float* __restrict__ pred2,
    const int* __restrict__ target, float* __restrict__ ws,
    float* __restrict__ out)
{
    // ---- XCD-aware bijective row swizzle (R14-proven: FETCH 27->7.6 MB) ----
    const int bid = blockIdx.x;
    const int xcd = bid & (NXCD - 1);
    const int idx = bid >> 3;
    const int q = NROWS / NXCD, r = NROWS % NXCD;
    const int row = (xcd < r ? xcd * (q + 1) : r * (q + 1) + (xcd - r) * q) + idx;

    const int n   = row / H_OUT;
    const int y   = row - n * H_OUT;
    const int tid = threadIdx.x;

    __shared__ float ry[2][C_CLS][ROWP];  // y-interpolated source rows
    __shared__ float wtab[C_CLS];
    __shared__ float sh_red[2][8];
    __shared__ bool  is_last;

    if (tid < C_CLS) wtab[tid] = c_class_w[tid];

    const float scl = (float)H_IN / (float)H_OUT;   // uniform fx step h

    // ---- column-run assignment ----
    int col, xs, npx;
    float fx0, hstep;
    if (tid < 97) {
        col = tid;
        xs  = ((2 * tid + 1) * 769 + 96) / 194;
        int xe = min(((2 * tid + 3) * 769 + 96) / 194, 769);
        npx = xe - xs;                    // 7 or 8
        fx0 = fmaf((float)xs + 0.5f, scl, -0.5f) - (float)col;
        hstep = scl;
    } else if (tid == 97) {
        col = 0; xs = 0; npx = 4; fx0 = 0.0f; hstep = 0.0f;   // left clamp run
    } else {
        col = 0; xs = 0; npx = 0; fx0 = 0.0f; hstep = 0.0f;
    }

    // ---- prefetch this thread's targets (latency hides under staging) ----
    const int rowbase = (n * H_OUT + y) * W_OUT;
    int tg[8];
    #pragma unroll
    for (int k = 0; k < 8; ++k)
        tg[k] = target[rowbase + min(xs + k, W_OUT - 1)];

    // ---- y-interp params (uniform over row) ----
    float sy = fmaxf(fmaf((float)y + 0.5f, scl, -0.5f), 0.0f);
    int   y0 = min((int)sy, H_IN - 1);
    float fy = sy - (float)y0;
    int   y1 = min(y0 + 1, H_IN - 1);

    // ---- stage y-interpolated rows into LDS: FULLY UNROLLED so all global
    //      loads issue back-to-back (1-2 latency exposures, not ~15) ----
    const float* __restrict__ b1 = pred1 + (size_t)n * CHW_IN;
    const float* __restrict__ b2 = pred2 + (size_t)n * CHW_IN;
    #pragma unroll
    for (int s = 0; s < NSTAGE; ++s) {
        int j = tid + s * BLKT;
        if (j < C_CLS * W_IN) {
            int c = j / W_IN;
            int x = j - c * W_IN;
            int o0 = c * HW_IN + y0 * W_IN + x;
            int o1 = c * HW_IN + y1 * W_IN + x;
            float a0 = b1[o0], a1 = b1[o1];
            float c0 = b2[o0], c1 = b2[o1];
            float r1 = fmaf(fy, a1 - a0, a0);
            float r2 = fmaf(fy, c1 - c0, c0);
            ry[0][c][x] = r1;
            ry[1][c][x] = r2;
            if (x == W_IN - 1) {
                ry[0][c][W_IN] = r1;
                ry[1][c][W_IN] = r2;
            }
        }
    }
    __syncthreads();

    // ---- softmax denominators: incremental exponentials along the run ----
    float s1[8], s2[8];
    #pragma unroll
    for (int k = 0; k < 8; ++k) { s1[k] = 0.f; s2[k] = 0.f; }

    #pragma unroll
    for (int c = 0; c < C_CLS; ++c) {
        float a1v = ry[0][c][col], b1v = ry[0][c][col + 1];
        float a2v = ry[1][c][col], b2v = ry[1][c][col + 1];
        float d1 = b1v - a1v;
        float d2 = b2v - a2v;
        float e1 = __expf(fmaf(fx0, d1, a1v));
        float e2 = __expf(fmaf(fx0, d2, a2v));
        float g1 = __expf(hstep * d1);
        float g2 = __expf(hstep * d2);
        #pragma unroll
        for (int k = 0; k < 8; ++k) {
            s1[k] += e1; e1 *= g1;
            s2[k] += e2; e2 *= g2;
        }
    }

    // ---- per-pixel epilogue ----
    float a_nv = 0.f;
    float a_w1 = 0.f, a_wlp1 = 0.f, a_cle1 = 0.f;
    float a_w2 = 0.f, a_wlp2 = 0.f, a_cle2 = 0.f;

    #pragma unroll
    for (int k = 0; k < 8; ++k) {
        if (k < npx) {
            int t = tg[k];
            if (t != IGNORE_LBL) {
                int ts = t;
                float fxk = fmaf((float)k, hstep, fx0);
                float u0 = ry[0][ts][col], u1 = ry[0][ts][col + 1];
                float v0 = ry[1][ts][col], v1 = ry[1][ts][col + 1];
                float lt1 = fmaf(fxk, u1 - u0, u0);
                float lt2 = fmaf(fxk, v1 - v0, v0);
                float w   = wtab[ts];
                float nll1 = __logf(s1[k]) - lt1;
                float nll2 = __logf(s2[k]) - lt2;
                a_nv += 1.0f;

                if (nll1 >= NLL_THR) {            // p1 <= 0.7 (common)
                    a_w1 += w; a_wlp1 = fmaf(w, nll1, a_wlp1); a_cle1 += 1.f;
                } else {                          // rare: direct global hist
                    float p = __expf(-nll1);
                    int b = min(max((int)((p - 0.7f) * (109.f / 0.3f)), 0), NHI - 1);
                    atomicAdd(&ws[4 + b],   1.f);
                    atomicAdd(&ws[114 + b], w);
                    atomicAdd(&ws[224 + b], w * nll1);
                }
                if (nll2 >= NLL_THR) {            // p2 <= 0.7 (common)
                    a_w2 += w; a_wlp2 = fmaf(w, nll2, a_wlp2); a_cle2 += 1.f;
                } else {
                    float p = __expf(-nll2);
                    int b = min(max((int)((p - 0.7f) * (109.f / 0.3f)), 0), NHI - 1);
                    atomicAdd(&ws[ACC_STRIDE + 4 + b],   1.f);
                    atomicAdd(&ws[ACC_STRIDE + 114 + b], w);
                    atomicAdd(&ws[ACC_STRIDE + 224 + b], w * nll2);
                }
            }
        }
    }

    // ---- wave butterfly reduce, 7 values ----
    #pragma unroll
    for (int off = 32; off > 0; off >>= 1) {
        a_nv   += __shfl_down(a_nv, off);
        a_w1   += __shfl_down(a_w1, off);
        a_wlp1 += __shfl_down(a_wlp1, off);
        a_cle1 += __shfl_down(a_cle1, off);
        a_w2   += __shfl_down(a_w2, off);
        a_wlp2 += __shfl_down(a_wlp2, off);
        a_cle2 += __shfl_down(a_cle2, off);
    }
    int lane = tid & 63;
    int wv   = tid >> 6;                   // 0..1
    if (lane == 0) {
        sh_red[wv][0] = a_nv;
        sh_red[wv][1] = a_w1; sh_red[wv][2] = a_wlp1; sh_red[wv][3] = a_cle1;
        sh_red[wv][4] = a_w2; sh_red[wv][5] = a_wlp2; sh_red[wv][6] = a_cle2;
    }
    __syncthreads();
    if (tid == 0) {
        float rr[7] = {0, 0, 0, 0, 0, 0, 0};
        #pragma unroll
        for (int i = 0; i < 2; ++i)
            #pragma unroll
            for (int j = 0; j < 7; ++j) rr[j] += sh_red[i][j];
        float* acc = ws + SET_BASE + (bid & (NSETS - 1)) * 16;
        #pragma unroll
        for (int j = 0; j < 7; ++j) atomicAdd(&acc[j], rr[j]);

        // release all our ws writes, then take a ticket
        __threadfence();
        unsigned int t = atomicAdd((unsigned int*)(ws + TICKET), 1u);
        is_last = (t == (unsigned int)(NROWS - 1));
    }
    __syncthreads();

    // ---- last block performs the finalize (fold sets + OHEM logic) ----
    if (is_last && tid < 64) {
        __threadfence();                   // acquire: see all blocks' writes
        float v[7];
        #pragma unroll
        for (int k = 0; k < 7; ++k) v[k] = ws[SET_BASE + tid * 16 + k];
        #pragma unroll
        for (int off = 32; off > 0; off >>= 1) {
            #pragma unroll
            for (int k = 0; k < 7; ++k) v[k] += __shfl_down(v[k], off);
        }
        if (tid == 0) {
            float nv = v[0];
            float loss[2];
            for (int pr = 0; pr < 2; ++pr) {
                const float* a = ws + pr * ACC_STRIDE;
                float sw   = pr ? v[4] : v[1];
                float swlp = pr ? v[5] : v[2];
                float cle  = pr ? v[6] : v[3];
                float l;
                if (nv <= (float)MIN_KEPT) {
                    float tw = sw, twlp = swlp;
                    for (int b = 0; b < NHI; ++b) { tw += a[114 + b]; twlp += a[224 + b]; }
                    l = twlp / tw;
                } else if (cle >= (float)MIN_KEPT) {
                    l = swlp / sw;
                } else {
                    float cum = cle, tw = sw, twlp = swlp;
                    for (int b = 0; b < NHI; ++b) {
                        cum  += a[4 + b];
                        tw   += a[114 + b];
                        twlp += a[224 + b];
                        if (cum >= (float)MIN_KEPT) break;
                    }
                    l = twlp / tw;
                }
                loss[pr] = l;
            }
            out[0] = 0.4f * loss[0] + loss[1];
        }
    }
}

extern "C" void kernel_launch(void* const* d_in, const int* in_sizes, int n_in,
                              void* d_out, int out_size, void* d_ws, size_t ws_size,
                              hipStream_t stream)
{
    const float* pred1  = (const float*)d_in[0];
    const float* pred2  = (const float*)d_in[1];
    const int*   target = (const int*)d_in[2];
    float* out = (float*)d_out;
    float* ws  = (float*)d_ws;

    hipMemsetAsync(d_ws, 0, WS_ZERO_FLOATS * sizeof(float), stream);

    ohem_row<<<dim3(NROWS), BLKT, 0, stream>>>(pred1, pred2, target, ws, out);
}

// Round 17
// 44.009 us; speedup vs baseline: 1.8089x; 1.8089x over previous
//
#include <hip/hip_runtime.h>
#include <math.h>

#define C_CLS   19
#define H_IN    97
#define W_IN    97
#define HW_IN   (H_IN * W_IN)
#define CHW_IN  (C_CLS * HW_IN)
#define H_OUT   769
#define W_OUT   769
#define N_BATCH 4
#define NROWS   (N_BATCH * H_OUT)    // 3076
#define NHALF   (NROWS * 2)          // 6152 = 8 * 769 exactly
#define NXCD    8
#define IGNORE_LBL 255
#define MIN_KEPT   100000
#define NHI     110
#define ACC_STRIDE 1024
#define NSETS   64                   // striped accumulator sets (R4-proven)
#define SET_BASE 2048
#define NLL_THR 0.35667494f          // -ln(0.7)
#define SCOLS   52                   // staged source columns per half-row
#define BLKT    128

__device__ const float c_class_w[C_CLS] = {
    0.8373f, 0.918f,  0.866f,  1.0345f, 1.0166f, 0.9969f, 0.9754f,
    1.0489f, 0.8786f, 1.0023f, 0.9539f, 0.9843f, 1.1116f, 0.9037f,
    1.0865f, 1.0955f, 1.0865f, 1.1529f, 1.0507f};

// ws layout (floats):
// [4..333]   hist pred1: cnt/sum_w/sum_wnll (stride 110)
// [1028..1357] hist pred2
// [2048 + s*16 + k] striped set s (0=nv 1=w1 2=wlp1 3=cle1 4=w2 5=wlp2 6=cle2)

__global__ __launch_bounds__(BLKT) void ohem_half(
    const float* __restrict__ pred1, const float* __restrict__ pred2,
    const int* __restrict__ target, float* __restrict__ ws)
{
    // ---- XCD-aware swizzle over half-row units (6152 = 8*769: exact) ----
    // Each XCD gets a contiguous band of 769 half-rows (~385 rows ≈ 1.5 MB
    // pred slab + target slab -> fits per-XCD 4 MB L2). R14-proven.
    const int bid = blockIdx.x;
    const int u   = (bid & (NXCD - 1)) * (NHALF / NXCD) + (bid >> 3);
    const int row = u >> 1;
    const int h   = u & 1;               // 0: px 0..384, 1: px 385..768

    const int n   = row / H_OUT;
    const int y   = row - n * H_OUT;
    const int tid = threadIdx.x;

    __shared__ float ry[2][C_CLS][SCOLS];  // y-interpolated source cols (half)
    __shared__ float wtab[C_CLS];
    __shared__ float sh_red[2][8];

    if (tid < C_CLS) wtab[tid] = c_class_w[tid];

    const float scl = (float)H_IN / (float)H_OUT;   // uniform fx step h

    // ---- half-run geometry (4 px per thread, R12-proven) ----
    const int ncols = h ? 49 : 48;       // cols 48..96 | cols 0..47
    const int cbase = h * 48;
    int col, xs_h, npx;
    float fx0, hstep;
    if (tid < 2 * ncols) {
        int cl   = tid >> 1;
        col      = cbase + cl;
        int xs   = ((2 * col + 1) * 769 + 96) / 194;
        int xe   = min(((2 * col + 3) * 769 + 96) / 194, 769);
        int half = tid & 1;
        xs_h = xs + half * 4;
        npx  = half ? max(xe - xs - 4, 0) : min(xe - xs, 4);
        fx0  = fmaf((float)xs_h + 0.5f, scl, -0.5f) - (float)col;
        hstep = scl;
    } else if (h == 0 && tid == 96) {    // left clamp region: px 0..3, fx=0
        col = 0; xs_h = 0; npx = 4; fx0 = 0.0f; hstep = 0.0f;
    } else {
        col = cbase; xs_h = h ? 385 : 0; npx = 0; fx0 = 0.0f; hstep = 0.0f;
    }

    // ---- prefetch this thread's targets (latency hides under staging) ----
    const int rowbase = (n * H_OUT + y) * W_OUT;
    int tg[4];
    #pragma unroll
    for (int k = 0; k < 4; ++k)
        tg[k] = target[rowbase + min(xs_h + k, W_OUT - 1)];

    // ---- y-interp params (uniform over row) ----
    float sy = fmaxf(fmaf((float)y + 0.5f, scl, -0.5f), 0.0f);
    int   y0 = min((int)sy, H_IN - 1);
    float fy = sy - (float)y0;
    int   y1 = min(y0 + 1, H_IN - 1);

    // ---- stage y-interpolated half-row cols into LDS (L2-local) ----
    const float* __restrict__ b1 = pred1 + (size_t)n * CHW_IN;
    const float* __restrict__ b2 = pred2 + (size_t)n * CHW_IN;
    for (int j = tid; j < C_CLS * SCOLS; j += BLKT) {
        int c = j / SCOLS;
        int x = j - c * SCOLS;
        int g = min(cbase + x, W_IN - 1);       // clamp pads the right edge
        int o0 = c * HW_IN + y0 * W_IN + g;
        int o1 = c * HW_IN + y1 * W_IN + g;
        float a0 = b1[o0], a1 = b1[o1];
        float c0 = b2[o0], c1 = b2[o1];
        ry[0][c][x] = fmaf(fy, a1 - a0, a0);
        ry[1][c][x] = fmaf(fy, c1 - c0, c0);
    }
    __syncthreads();

    // ---- softmax denominators: incremental exponentials along the 4-px run ----
    const int ix = col - cbase;                 // 0..48; ix+1 <= 49 < SCOLS
    float s1[4] = {0.f, 0.f, 0.f, 0.f};
    float s2[4] = {0.f, 0.f, 0.f, 0.f};

    #pragma unroll
    for (int c = 0; c < C_CLS; ++c) {
        float a1v = ry[0][c][ix], b1v = ry[0][c][ix + 1];
        float a2v = ry[1][c][ix], b2v = ry[1][c][ix + 1];
        float d1 = b1v - a1v;
        float d2 = b2v - a2v;
        float e1 = __expf(fmaf(fx0, d1, a1v));
        float e2 = __expf(fmaf(fx0, d2, a2v));
        float g1 = __expf(hstep * d1);
        float g2 = __expf(hstep * d2);
        #pragma unroll
        for (int k = 0; k < 4; ++k) {
            s1[k] += e1; e1 *= g1;
            s2[k] += e2; e2 *= g2;
        }
    }

    // ---- per-pixel epilogue ----
    float a_nv = 0.f;
    float a_w1 = 0.f, a_wlp1 = 0.f, a_cle1 = 0.f;
    float a_w2 = 0.f, a_wlp2 = 0.f, a_cle2 = 0.f;

    #pragma unroll
    for (int k = 0; k < 4; ++k) {
        if (k < npx) {
            int t = tg[k];
            if (t != IGNORE_LBL) {
                int ts = t;
                float fxk = fmaf((float)k, hstep, fx0);
                float u0 = ry[0][ts][ix], u1 = ry[0][ts][ix + 1];
                float v0 = ry[1][ts][ix], v1 = ry[1][ts][ix + 1];
                float lt1 = fmaf(fxk, u1 - u0, u0);
                float lt2 = fmaf(fxk, v1 - v0, v0);
                float w   = wtab[ts];
                float nll1 = __logf(s1[k]) - lt1;
                float nll2 = __logf(s2[k]) - lt2;
                a_nv += 1.0f;

                if (nll1 >= NLL_THR) {            // p1 <= 0.7 (common)
                    a_w1 += w; a_wlp1 = fmaf(w, nll1, a_wlp1); a_cle1 += 1.f;
                } else {                          // rare: direct global hist
                    float p = __expf(-nll1);
                    int b = min(max((int)((p - 0.7f) * (109.f / 0.3f)), 0), NHI - 1);
                    atomicAdd(&ws[4 + b],   1.f);
                    atomicAdd(&ws[114 + b], w);
                    atomicAdd(&ws[224 + b], w * nll1);
                }
                if (nll2 >= NLL_THR) {            // p2 <= 0.7 (common)
                    a_w2 += w; a_wlp2 = fmaf(w, nll2, a_wlp2); a_cle2 += 1.f;
                } else {
                    float p = __expf(-nll2);
                    int b = min(max((int)((p - 0.7f) * (109.f / 0.3f)), 0), NHI - 1);
                    atomicAdd(&ws[ACC_STRIDE + 4 + b],   1.f);
                    atomicAdd(&ws[ACC_STRIDE + 114 + b], w);
                    atomicAdd(&ws[ACC_STRIDE + 224 + b], w * nll2);
                }
            }
        }
    }

    // ---- wave butterfly reduce, 7 values ----
    #pragma unroll
    for (int off = 32; off > 0; off >>= 1) {
        a_nv   += __shfl_down(a_nv, off);
        a_w1   += __shfl_down(a_w1, off);
        a_wlp1 += __shfl_down(a_wlp1, off);
        a_cle1 += __shfl_down(a_cle1, off);
        a_w2   += __shfl_down(a_w2, off);
        a_wlp2 += __shfl_down(a_wlp2, off);
        a_cle2 += __shfl_down(a_cle2, off);
    }
    int lane = tid & 63;
    int wv   = tid >> 6;                   // 0..1
    if (lane == 0) {
        sh_red[wv][0] = a_nv;
        sh_red[wv][1] = a_w1; sh_red[wv][2] = a_wlp1; sh_red[wv][3] = a_cle1;
        sh_red[wv][4] = a_w2; sh_red[wv][5] = a_wlp2; sh_red[wv][6] = a_cle2;
    }
    __syncthreads();
    if (tid == 0) {
        float rr[7] = {0, 0, 0, 0, 0, 0, 0};
        #pragma unroll
        for (int i = 0; i < 2; ++i)
            #pragma unroll
            for (int j = 0; j < 7; ++j) rr[j] += sh_red[i][j];
        float* acc = ws + SET_BASE + (bid & (NSETS - 1)) * 16;
        #pragma unroll
        for (int j = 0; j < 7; ++j) atomicAdd(&acc[j], rr[j]);
    }
}

__global__ void ohem_finalize(const float* __restrict__ ws, float* __restrict__ out)
{
    int lane = threadIdx.x;   // 0..63
    float v[7];
    #pragma unroll
    for (int k = 0; k < 7; ++k) v[k] = ws[SET_BASE + lane * 16 + k];
    #pragma unroll
    for (int off = 32; off > 0; off >>= 1) {
        #pragma unroll
        for (int k = 0; k < 7; ++k) v[k] += __shfl_down(v[k], off);
    }
    if (lane != 0) return;

    float nv = v[0];
    float loss[2];
    for (int pr = 0; pr < 2; ++pr) {
        const float* a = ws + pr * ACC_STRIDE;
        float sw   = pr ? v[4] : v[1];
        float swlp = pr ? v[5] : v[2];
        float cle  = pr ? v[6] : v[3];
        float l;
        if (nv <= (float)MIN_KEPT) {
            float tw = sw, twlp = swlp;
            for (int b = 0; b < NHI; ++b) { tw += a[114 + b]; twlp += a[224 + b]; }
            l = twlp / tw;
        } else if (cle >= (float)MIN_KEPT) {
            l = swlp / sw;
        } else {
            float cum = cle, tw = sw, twlp = swlp;
            for (int b = 0; b < NHI; ++b) {
                cum  += a[4 + b];
                tw   += a[114 + b];
                twlp += a[224 + b];
                if (cum >= (float)MIN_KEPT) break;
            }
            l = twlp / tw;
        }
        loss[pr] = l;
    }
    out[0] = 0.4f * loss[0] + loss[1];
}

extern "C" void kernel_launch(void* const* d_in, const int* in_sizes, int n_in,
                              void* d_out, int out_size, void* d_ws, size_t ws_size,
                              hipStream_t stream)
{
    const float* pred1  = (const float*)d_in[0];
    const float* pred2  = (const float*)d_in[1];
    const int*   target = (const int*)d_in[2];
    float* out = (float*)d_out;
    float* ws  = (float*)d_ws;

    hipMemsetAsync(d_ws, 0, (SET_BASE + NSETS * 16) * sizeof(float), stream);

    ohem_half<<<dim3(NHALF), BLKT, 0, stream>>>(pred1, pred2, target, ws);
    ohem_finalize<<<1, 64, 0, stream>>>(ws, out);
}

// Round 18
// 42.940 us; speedup vs baseline: 1.8540x; 1.0249x over previous
//
#include <hip/hip_runtime.h>
#include <math.h>

#define C_CLS   19
#define H_IN    97
#define W_IN    97
#define HW_IN   (H_IN * W_IN)
#define CHW_IN  (C_CLS * HW_IN)
#define H_OUT   769
#define W_OUT   769
#define N_BATCH 4
#define NROWS   (N_BATCH * H_OUT)    // 3076
#define NXCD    8
#define IGNORE_LBL 255
#define MIN_KEPT   100000
#define NHI     110
#define ACC_STRIDE 1024
#define NSETS   64                   // striped accumulator sets (R4-proven)
#define SET_BASE 2048
#define NLL_THR 0.35667494f          // -ln(0.7)
#define XPAD    128                  // raw LDS row stride (pad absorbs lanes 97..127)
#define BLKT    128

__device__ const float c_class_w[C_CLS] = {
    0.8373f, 0.918f,  0.866f,  1.0345f, 1.0166f, 0.9969f, 0.9754f,
    1.0489f, 0.8786f, 1.0023f, 0.9539f, 0.9843f, 1.1116f, 0.9037f,
    1.0865f, 1.0955f, 1.0865f, 1.1529f, 1.0507f};

// ws layout (floats):
// [4..333]   hist pred1: cnt/sum_w/sum_wnll (stride 110)
// [1028..1357] hist pred2
// [2048 + s*16 + k] striped set s (0=nv 1=w1 2=wlp1 3=cle1 4=w2 5=wlp2 6=cle2)

typedef const __attribute__((address_space(1))) float gfloat;
typedef __attribute__((address_space(3))) float lfloat;

__global__ __launch_bounds__(BLKT) void ohem_row(
    const float* __restrict__ pred1, const float* __restrict__ pred2,
    const int* __restrict__ target, float* __restrict__ ws)
{
    // ---- XCD-aware bijective row swizzle (R14-proven: FETCH 27->7.6 MB) ----
    const int bid = blockIdx.x;
    const int xcd = bid & (NXCD - 1);
    const int idx = bid >> 3;
    const int q = NROWS / NXCD, r = NROWS % NXCD;
    const int row = (xcd < r ? xcd * (q + 1) : r * (q + 1) + (xcd - r) * q) + idx;

    const int n   = row / H_OUT;
    const int y   = row - n * H_OUT;
    const int tid = threadIdx.x;

    __shared__ float raw[2][2][C_CLS][XPAD];  // [pred][yrow][ch][x] RAW rows
    __shared__ float wtab[C_CLS];
    __shared__ float sh_red[2][8];

    if (tid < C_CLS) wtab[tid] = c_class_w[tid];

    const float scl = (float)H_IN / (float)H_OUT;   // uniform fx step h

    // ---- column-run assignment (R14-proven geometry) ----
    int col, xs, npx;
    float fx0, hstep;
    if (tid < 97) {
        col = tid;
        xs  = ((2 * tid + 1) * 769 + 96) / 194;
        int xe = min(((2 * tid + 3) * 769 + 96) / 194, 769);
        npx = xe - xs;                    // 7 or 8
        fx0 = fmaf((float)xs + 0.5f, scl, -0.5f) - (float)col;
        hstep = scl;
    } else if (tid == 97) {
        col = 0; xs = 0; npx = 4; fx0 = 0.0f; hstep = 0.0f;   // left clamp run
    } else {
        col = 0; xs = 0; npx = 0; fx0 = 0.0f; hstep = 0.0f;
    }
    const int ix  = col;
    const int ixp = min(col + 1, W_IN - 1);   // right-edge clamp (b == a)

    // ---- prefetch this thread's targets (independent, overlap staging) ----
    const int rowbase = (n * H_OUT + y) * W_OUT;
    int tg[8];
    #pragma unroll
    for (int k = 0; k < 8; ++k)
        tg[k] = target[rowbase + min(xs + k, W_OUT - 1)];

    // ---- y-interp params (uniform over row) ----
    float sy = fmaxf(fmaf((float)y + 0.5f, scl, -0.5f), 0.0f);
    int   y0 = min((int)sy, H_IN - 1);
    float fy = sy - (float)y0;
    int   y1 = min(y0 + 1, H_IN - 1);

    // ---- RAW async staging: global_load_lds, no VGPR round-trip.
    //      All 76 issues are fire-and-forget; ONE vmcnt drain at the barrier
    //      (vs ~15-29 serialized L2-latency exposures through registers). ----
    {
        const int wv = tid >> 6;              // wave id, wave-uniform
        const int ln = tid & 63;
        const int x  = tid;                   // staged x == tid (<97 active)
        const bool xok = x < W_IN;
        const int xc = min(x, W_IN - 1);      // safe source even if masked-lane issues
        const float* s00 = pred1 + (size_t)n * CHW_IN + y0 * W_IN + xc;
        const float* s01 = pred1 + (size_t)n * CHW_IN + y1 * W_IN + xc;
        const float* s10 = pred2 + (size_t)n * CHW_IN + y0 * W_IN + xc;
        const float* s11 = pred2 + (size_t)n * CHW_IN + y1 * W_IN + xc;
        #pragma unroll
        for (int c = 0; c < C_CLS; ++c) {
            const int co = c * HW_IN;
            if (xok) {
                __builtin_amdgcn_global_load_lds((gfloat*)(s00 + co),
                    (lfloat*)&raw[0][0][c][wv * 64], 4, 0, 0);
                __builtin_amdgcn_global_load_lds((gfloat*)(s01 + co),
                    (lfloat*)&raw[0][1][c][wv * 64], 4, 0, 0);
                __builtin_amdgcn_global_load_lds((gfloat*)(s10 + co),
                    (lfloat*)&raw[1][0][c][wv * 64], 4, 0, 0);
                __builtin_amdgcn_global_load_lds((gfloat*)(s11 + co),
                    (lfloat*)&raw[1][1][c][wv * 64], 4, 0, 0);
            }
        }
        (void)ln;
    }
    __syncthreads();

    // ---- y-lerp helper (each column owned by exactly one thread) ----
    auto rdy = [&](int p, int c, int i) -> float {
        float a = raw[p][0][c][i];
        float b = raw[p][1][c][i];
        return fmaf(fy, b - a, a);
    };

    // ---- softmax denominators: incremental exponentials along the run ----
    float s1[8], s2[8];
    #pragma unroll
    for (int k = 0; k < 8; ++k) { s1[k] = 0.f; s2[k] = 0.f; }

    #pragma unroll
    for (int c = 0; c < C_CLS; ++c) {
        float lo1 = rdy(0, c, ix), hi1 = rdy(0, c, ixp);
        float lo2 = rdy(1, c, ix), hi2 = rdy(1, c, ixp);
        float d1 = hi1 - lo1;
        float d2 = hi2 - lo2;
        float e1 = __expf(fmaf(fx0, d1, lo1));
        float e2 = __expf(fmaf(fx0, d2, lo2));
        float g1 = __expf(hstep * d1);
        float g2 = __expf(hstep * d2);
        #pragma unroll
        for (int k = 0; k < 8; ++k) {
            s1[k] += e1; e1 *= g1;
            s2[k] += e2; e2 *= g2;
        }
    }

    // ---- per-pixel epilogue ----
    float a_nv = 0.f;
    float a_w1 = 0.f, a_wlp1 = 0.f, a_cle1 = 0.f;
    float a_w2 = 0.f, a_wlp2 = 0.f, a_cle2 = 0.f;

    #pragma unroll
    for (int k = 0; k < 8; ++k) {
        if (k < npx) {
            int t = tg[k];
            if (t != IGNORE_LBL) {
                int ts = t;
                float fxk = fmaf((float)k, hstep, fx0);
                float u0 = rdy(0, ts, ix), u1 = rdy(0, ts, ixp);
                float v0 = rdy(1, ts, ix), v1 = rdy(1, ts, ixp);
                float lt1 = fmaf(fxk, u1 - u0, u0);
                float lt2 = fmaf(fxk, v1 - v0, v0);
                float w   = wtab[ts];
                float nll1 = __logf(s1[k]) - lt1;
                float nll2 = __logf(s2[k]) - lt2;
                a_nv += 1.0f;

                if (nll1 >= NLL_THR) {            // p1 <= 0.7 (common)
                    a_w1 += w; a_wlp1 = fmaf(w, nll1, a_wlp1); a_cle1 += 1.f;
                } else {                          // rare: direct global hist
                    float p = __expf(-nll1);
                    int b = min(max((int)((p - 0.7f) * (109.f / 0.3f)), 0), NHI - 1);
                    atomicAdd(&ws[4 + b],   1.f);
                    atomicAdd(&ws[114 + b], w);
                    atomicAdd(&ws[224 + b], w * nll1);
                }
                if (nll2 >= NLL_THR) {            // p2 <= 0.7 (common)
                    a_w2 += w; a_wlp2 = fmaf(w, nll2, a_wlp2); a_cle2 += 1.f;
                } else {
                    float p = __expf(-nll2);
                    int b = min(max((int)((p - 0.7f) * (109.f / 0.3f)), 0), NHI - 1);
                    atomicAdd(&ws[ACC_STRIDE + 4 + b],   1.f);
                    atomicAdd(&ws[ACC_STRIDE + 114 + b], w);
                    atomicAdd(&ws[ACC_STRIDE + 224 + b], w * nll2);
                }
            }
        }
    }

    // ---- wave butterfly reduce, 7 values ----
    #pragma unroll
    for (int off = 32; off > 0; off >>= 1) {
        a_nv   += __shfl_down(a_nv, off);
        a_w1   += __shfl_down(a_w1, off);
        a_wlp1 += __shfl_down(a_wlp1, off);
        a_cle1 += __shfl_down(a_cle1, off);
        a_w2   += __shfl_down(a_w2, off);
        a_wlp2 += __shfl_down(a_wlp2, off);
        a_cle2 += __shfl_down(a_cle2, off);
    }
    int lane = tid & 63;
    int wv2  = tid >> 6;                   // 0..1
    if (lane == 0) {
        sh_red[wv2][0] = a_nv;
        sh_red[wv2][1] = a_w1; sh_red[wv2][2] = a_wlp1; sh_red[wv2][3] = a_cle1;
        sh_red[wv2][4] = a_w2; sh_red[wv2][5] = a_wlp2; sh_red[wv2][6] = a_cle2;
    }
    __syncthreads();
    if (tid == 0) {
        float rr[7] = {0, 0, 0, 0, 0, 0, 0};
        #pragma unroll
        for (int i = 0; i < 2; ++i)
            #pragma unroll
            for (int j = 0; j < 7; ++j) rr[j] += sh_red[i][j];
        float* acc = ws + SET_BASE + (bid & (NSETS - 1)) * 16;
        #pragma unroll
        for (int j = 0; j < 7; ++j) atomicAdd(&acc[j], rr[j]);
    }
}

__global__ void ohem_finalize(const float* __restrict__ ws, float* __restrict__ out)
{
    int lane = threadIdx.x;   // 0..63
    float v[7];
    #pragma unroll
    for (int k = 0; k < 7; ++k) v[k] = ws[SET_BASE + lane * 16 + k];
    #pragma unroll
    for (int off = 32; off > 0; off >>= 1) {
        #pragma unroll
        for (int k = 0; k < 7; ++k) v[k] += __shfl_down(v[k], off);
    }
    if (lane != 0) return;

    float nv = v[0];
    float loss[2];
    for (int pr = 0; pr < 2; ++pr) {
        const float* a = ws + pr * ACC_STRIDE;
        float sw   = pr ? v[4] : v[1];
        float swlp = pr ? v[5] : v[2];
        float cle  = pr ? v[6] : v[3];
        float l;
        if (nv <= (float)MIN_KEPT) {
            float tw = sw, twlp = swlp;
            for (int b = 0; b < NHI; ++b) { tw += a[114 + b]; twlp += a[224 + b]; }
            l = twlp / tw;
        } else if (cle >= (float)MIN_KEPT) {
            l = swlp / sw;
        } else {
            float cum = cle, tw = sw, twlp = swlp;
            for (int b = 0; b < NHI; ++b) {
                cum  += a[4 + b];
                tw   += a[114 + b];
                twlp += a[224 + b];
                if (cum >= (float)MIN_KEPT) break;
            }
            l = twlp / tw;
        }
        loss[pr] = l;
    }
    out[0] = 0.4f * loss[0] + loss[1];
}

extern "C" void kernel_launch(void* const* d_in, const int* in_sizes, int n_in,
                              void* d_out, int out_size, void* d_ws, size_t ws_size,
                              hipStream_t stream)
{
    const float* pred1  = (const float*)d_in[0];
    const float* pred2  = (const float*)d_in[1];
    const int*   target = (const int*)d_in[2];
    float* out = (float*)d_out;
    float* ws  = (float*)d_ws;

    hipMemsetAsync(d_ws, 0, (SET_BASE + NSETS * 16) * sizeof(float), stream);

    ohem_row<<<dim3(NROWS), BLKT, 0, stream>>>(pred1, pred2, target, ws);
    ohem_finalize<<<1, 64, 0, stream>>>(ws, out);
}

// Round 19
// 36.796 us; speedup vs baseline: 2.1635x; 1.1670x over previous
//
#include <hip/hip_runtime.h>
#include <math.h>

#define C_CLS   19
#define H_IN    97
#define W_IN    97
#define HW_IN   (H_IN * W_IN)
#define CHW_IN  (C_CLS * HW_IN)
#define H_OUT   769
#define W_OUT   769
#define N_BATCH 4
#define NROWS   (N_BATCH * H_OUT)    // 3076
#define NXCD    8
#define IGNORE_LBL 255
#define MIN_KEPT   100000
#define NHI     110
#define ACC_STRIDE 1024
#define NSETS   64                   // striped accumulator sets (R4-proven)
#define SET_BASE 2048
#define NLL_THR 0.35667494f          // -ln(0.7)
#define ROWP    100                  // padded LDS row length (>= 98)
#define BLKT    128
#define NSTAGE  15                   // ceil(19*97 / 128)

__device__ const float c_class_w[C_CLS] = {
    0.8373f, 0.918f,  0.866f,  1.0345f, 1.0166f, 0.9969f, 0.9754f,
    1.0489f, 0.8786f, 1.0023f, 0.9539f, 0.9843f, 1.1116f, 0.9037f,
    1.0865f, 1.0955f, 1.0865f, 1.1529f, 1.0507f};

// ws layout (floats):
// [4..333]   hist pred1: cnt/sum_w/sum_wnll (stride 110)
// [1028..1357] hist pred2
// [2048 + s*16 + k] striped set s (0=nv 1=w1 2=wlp1 3=cle1 4=w2 5=wlp2 6=cle2)

__global__ __launch_bounds__(BLKT) void ohem_row(
    const float* __restrict__ pred1, const float* __restrict__ pred2,
    const int* __restrict__ target, float* __restrict__ ws)
{
    // ---- XCD-aware bijective row swizzle (R14-proven: FETCH 27->7.6 MB) ----
    const int bid = blockIdx.x;
    const int xcd = bid & (NXCD - 1);
    const int idx = bid >> 3;
    const int q = NROWS / NXCD, r = NROWS % NXCD;
    const int row = (xcd < r ? xcd * (q + 1) : r * (q + 1) + (xcd - r) * q) + idx;

    const int n   = row / H_OUT;
    const int y   = row - n * H_OUT;
    const int tid = threadIdx.x;

    __shared__ float ry[2][C_CLS][ROWP];  // y-interpolated source rows
    __shared__ float wtab[C_CLS];
    __shared__ float sh_red[2][8];

    if (tid < C_CLS) wtab[tid] = c_class_w[tid];

    const float scl = (float)H_IN / (float)H_OUT;   // uniform fx step h

    // ---- column-run assignment ----
    int col, xs, npx;
    float fx0, hstep;
    if (tid < 97) {
        col = tid;
        xs  = ((2 * tid + 1) * 769 + 96) / 194;
        int xe = min(((2 * tid + 3) * 769 + 96) / 194, 769);
        npx = xe - xs;                    // 7 or 8
        fx0 = fmaf((float)xs + 0.5f, scl, -0.5f) - (float)col;
        hstep = scl;
    } else if (tid == 97) {
        col = 0; xs = 0; npx = 4; fx0 = 0.0f; hstep = 0.0f;   // left clamp run
    } else {
        col = 0; xs = 0; npx = 0; fx0 = 0.0f; hstep = 0.0f;
    }

    // ---- prefetch this thread's targets (latency hides under staging) ----
    const int rowbase = (n * H_OUT + y) * W_OUT;
    int tg[8];
    #pragma unroll
    for (int k = 0; k < 8; ++k)
        tg[k] = target[rowbase + min(xs + k, W_OUT - 1)];

    // ---- y-interp params (uniform over row) ----
    float sy = fmaxf(fmaf((float)y + 0.5f, scl, -0.5f), 0.0f);
    int   y0 = min((int)sy, H_IN - 1);
    float fy = sy - (float)y0;
    int   y1 = min(y0 + 1, H_IN - 1);

    // ---- stage y-interpolated rows into LDS: FULLY UNROLLED (static trip
    //      count) so the scheduler can hoist loads across copies; cuts the
    //      ~15 serialized L2-latency exposures of the rolled loop. This is
    //      the ONLY change vs R14 (R16's regression was its threadfence). ----
    const float* __restrict__ b1 = pred1 + (size_t)n * CHW_IN;
    const float* __restrict__ b2 = pred2 + (size_t)n * CHW_IN;
    #pragma unroll
    for (int s = 0; s < NSTAGE; ++s) {
        int j = tid + s * BLKT;
        if (j < C_CLS * W_IN) {
            int c = j / W_IN;
            int x = j - c * W_IN;
            int o0 = c * HW_IN + y0 * W_IN + x;
            int o1 = c * HW_IN + y1 * W_IN + x;
            float a0 = b1[o0], a1 = b1[o1];
            float c0 = b2[o0], c1 = b2[o1];
            float r1 = fmaf(fy, a1 - a0, a0);
            float r2 = fmaf(fy, c1 - c0, c0);
            ry[0][c][x] = r1;
            ry[1][c][x] = r2;
            if (x == W_IN - 1) {
                ry[0][c][W_IN] = r1;
                ry[1][c][W_IN] = r2;
            }
        }
    }
    __syncthreads();

    // ---- softmax denominators: incremental exponentials along the run ----
    float s1[8], s2[8];
    #pragma unroll
    for (int k = 0; k < 8; ++k) { s1[k] = 0.f; s2[k] = 0.f; }

    #pragma unroll
    for (int c = 0; c < C_CLS; ++c) {
        float a1v = ry[0][c][col], b1v = ry[0][c][col + 1];
        float a2v = ry[1][c][col], b2v = ry[1][c][col + 1];
        float d1 = b1v - a1v;
        float d2 = b2v - a2v;
        float e1 = __expf(fmaf(fx0, d1, a1v));
        float e2 = __expf(fmaf(fx0, d2, a2v));
        float g1 = __expf(hstep * d1);
        float g2 = __expf(hstep * d2);
        #pragma unroll
        for (int k = 0; k < 8; ++k) {
            s1[k] += e1; e1 *= g1;
            s2[k] += e2; e2 *= g2;
        }
    }

    // ---- per-pixel epilogue ----
    float a_nv = 0.f;
    float a_w1 = 0.f, a_wlp1 = 0.f, a_cle1 = 0.f;
    float a_w2 = 0.f, a_wlp2 = 0.f, a_cle2 = 0.f;

    #pragma unroll
    for (int k = 0; k < 8; ++k) {
        if (k < npx) {
            int t = tg[k];
            if (t != IGNORE_LBL) {
                int ts = t;
                float fxk = fmaf((float)k, hstep, fx0);
                float u0 = ry[0][ts][col], u1 = ry[0][ts][col + 1];
                float v0 = ry[1][ts][col], v1 = ry[1][ts][col + 1];
                float lt1 = fmaf(fxk, u1 - u0, u0);
                float lt2 = fmaf(fxk, v1 - v0, v0);
                float w   = wtab[ts];
                float nll1 = __logf(s1[k]) - lt1;
                float nll2 = __logf(s2[k]) - lt2;
                a_nv += 1.0f;

                if (nll1 >= NLL_THR) {            // p1 <= 0.7 (common)
                    a_w1 += w; a_wlp1 = fmaf(w, nll1, a_wlp1); a_cle1 += 1.f;
                } else {                          // rare: direct global hist
                    float p = __expf(-nll1);
                    int b = min(max((int)((p - 0.7f) * (109.f / 0.3f)), 0), NHI - 1);
                    atomicAdd(&ws[4 + b],   1.f);
                    atomicAdd(&ws[114 + b], w);
                    atomicAdd(&ws[224 + b], w * nll1);
                }
                if (nll2 >= NLL_THR) {            // p2 <= 0.7 (common)
                    a_w2 += w; a_wlp2 = fmaf(w, nll2, a_wlp2); a_cle2 += 1.f;
                } else {
                    float p = __expf(-nll2);
                    int b = min(max((int)((p - 0.7f) * (109.f / 0.3f)), 0), NHI - 1);
                    atomicAdd(&ws[ACC_STRIDE + 4 + b],   1.f);
                    atomicAdd(&ws[ACC_STRIDE + 114 + b], w);
                    atomicAdd(&ws[ACC_STRIDE + 224 + b], w * nll2);
                }
            }
        }
    }

    // ---- wave butterfly reduce, 7 values ----
    #pragma unroll
    for (int off = 32; off > 0; off >>= 1) {
        a_nv   += __shfl_down(a_nv, off);
        a_w1   += __shfl_down(a_w1, off);
        a_wlp1 += __shfl_down(a_wlp1, off);
        a_cle1 += __shfl_down(a_cle1, off);
        a_w2   += __shfl_down(a_w2, off);
        a_wlp2 += __shfl_down(a_wlp2, off);
        a_cle2 += __shfl_down(a_cle2, off);
    }
    int lane = tid & 63;
    int wv   = tid >> 6;                   // 0..1
    if (lane == 0) {
        sh_red[wv][0] = a_nv;
        sh_red[wv][1] = a_w1; sh_red[wv][2] = a_wlp1; sh_red[wv][3] = a_cle1;
        sh_red[wv][4] = a_w2; sh_red[wv][5] = a_wlp2; sh_red[wv][6] = a_cle2;
    }
    __syncthreads();
    if (tid == 0) {
        float rr[7] = {0, 0, 0, 0, 0, 0, 0};
        #pragma unroll
        for (int i = 0; i < 2; ++i)
            #pragma unroll
            for (int j = 0; j < 7; ++j) rr[j] += sh_red[i][j];
        float* acc = ws + SET_BASE + (bid & (NSETS - 1)) * 16;
        #pragma unroll
        for (int j = 0; j < 7; ++j) atomicAdd(&acc[j], rr[j]);
    }
}

__global__ void ohem_finalize(const float* __restrict__ ws, float* __restrict__ out)
{
    int lane = threadIdx.x;   // 0..63
    float v[7];
    #pragma unroll
    for (int k = 0; k < 7; ++k) v[k] = ws[SET_BASE + lane * 16 + k];
    #pragma unroll
    for (int off = 32; off > 0; off >>= 1) {
        #pragma unroll
        for (int k = 0; k < 7; ++k) v[k] += __shfl_down(v[k], off);
    }
    if (lane != 0) return;

    float nv = v[0];
    float loss[2];
    for (int pr = 0; pr < 2; ++pr) {
        const float* a = ws + pr * ACC_STRIDE;
        float sw   = pr ? v[4] : v[1];
        float swlp = pr ? v[5] : v[2];
        float cle  = pr ? v[6] : v[3];
        float l;
        if (nv <= (float)MIN_KEPT) {
            float tw = sw, twlp = swlp;
            for (int b = 0; b < NHI; ++b) { tw += a[114 + b]; twlp += a[224 + b]; }
            l = twlp / tw;
        } else if (cle >= (float)MIN_KEPT) {
            l = swlp / sw;
        } else {
            float cum = cle, tw = sw, twlp = swlp;
            for (int b = 0; b < NHI; ++b) {
                cum  += a[4 + b];
                tw   += a[114 + b];
                twlp += a[224 + b];
                if (cum >= (float)MIN_KEPT) break;
            }
            l = twlp / tw;
        }
        loss[pr] = l;
    }
    out[0] = 0.4f * loss[0] + loss[1];
}

extern "C" void kernel_launch(void* const* d_in, const int* in_sizes, int n_in,
                              void* d_out, int out_size, void* d_ws, size_t ws_size,
                              hipStream_t stream)
{
    const float* pred1  = (const float*)d_in[0];
    const float* pred2  = (const float*)d_in[1];
    const int*   target = (const int*)d_in[2];
    float* out = (float*)d_out;
    float* ws  = (float*)d_ws;

    hipMemsetAsync(d_ws, 0, (SET_BASE + NSETS * 16) * sizeof(float), stream);

    ohem_row<<<dim3(NROWS), BLKT, 0, stream>>>(pred1, pred2, target, ws);
    ohem_finalize<<<1, 64, 0, stream>>>(ws, out);
}